// Round 9
// baseline (180.884 us; speedup 1.0000x reference)
//
#include <hip/hip_runtime.h>

#define B_ 8
#define C_ 128
#define CI_ 64
#define N_ 4096

typedef _Float16 f16x8 __attribute__((ext_vector_type(8)));
typedef _Float16 f16x4 __attribute__((ext_vector_type(4)));
typedef float   f32x4  __attribute__((ext_vector_type(4)));

// Swizzled operand layouts (per batch, 256 chunks of 16 rows):
//  thS/phS: elem[((b*256+mc)*2 + half)*512 + lane*8 + e]
//           = X[row = mc*16 + (lane&15)][ci = half*32 + (lane>>4)*8 + e]
//  gS:      elem[(b*256+mc)*1024 + lane*16 + (ct*4 + j)]
//           = g[ci = ct*16 + (lane&15)][m = mc*16 + (lane>>4)*4 + j]
// Chunk stride is 1024 elems in all three; every streamed wave load is a
// fully-coalesced 1 KiB dwordx4.

// ---------------------------------------------------------------------------
// K0: transpose x [B][C][N] fp32 -> xT [B][N][C] f16 (64x64 LDS tiles)
// ---------------------------------------------------------------------------
__global__ __launch_bounds__(256) void k_transpose(const float* __restrict__ x,
                                                   _Float16* __restrict__ xT)
{
    __shared__ float tile[64][65];
    int b = blockIdx.z, c0 = blockIdx.y * 64, n0 = blockIdx.x * 64;
    int tx = threadIdx.x & 63, ty = threadIdx.x >> 6;
#pragma unroll
    for (int i = 0; i < 16; i++) {
        int c = ty + i * 4;
        tile[c][tx] = x[((size_t)b * C_ + c0 + c) * N_ + n0 + tx];
    }
    __syncthreads();
#pragma unroll
    for (int i = 0; i < 16; i++) {
        int n = ty + i * 4;
        xT[((size_t)b * N_ + n0 + n) * C_ + c0 + tx] = (_Float16)tile[tx][n];
    }
}

// ---------------------------------------------------------------------------
// K0b: convert the four weight matrices fp32 -> f16 (each 8192 elems)
// ---------------------------------------------------------------------------
__global__ __launch_bounds__(256) void k_wconv(
    const float* __restrict__ thw, const float* __restrict__ phw,
    const float* __restrict__ gw,  const float* __restrict__ ww,
    _Float16* __restrict__ wTh, _Float16* __restrict__ wPh,
    _Float16* __restrict__ wG,  _Float16* __restrict__ wW)
{
    int i = blockIdx.x * 256 + threadIdx.x;   // 0..32767
    int which = i >> 13, j = i & 8191;
    if (which == 0)      wTh[j] = (_Float16)thw[j];
    else if (which == 1) wPh[j] = (_Float16)phw[j];
    else if (which == 2) wG[j]  = (_Float16)gw[j];
    else                 wW[j]  = (_Float16)ww[j];
}

// ---------------------------------------------------------------------------
// K1: projections -> thS (pre-scaled by log2e), phS, gS in swizzled layouts.
// MFMA results are scattered into LDS (cheap b16 writes), then stored to
// global with fully-coalesced f16x8 wave stores (swizzled layout is
// chunk-contiguous: a block's 4 chunks = one flat 4096-elem range/buffer).
// ---------------------------------------------------------------------------
__global__ __launch_bounds__(256) void k_proj(
    const _Float16* __restrict__ xT,
    const _Float16* __restrict__ wTh, const _Float16* __restrict__ wPh,
    const _Float16* __restrict__ wG,
    const float* __restrict__ bTh, const float* __restrict__ bPh,
    const float* __restrict__ bG,
    _Float16* __restrict__ thS, _Float16* __restrict__ phS,
    _Float16* __restrict__ gS)
{
    __shared__ _Float16 thL[4096], phL[4096], gL[4096];   // 24 KiB
    const float kLog2e = 1.44269504088896f;
    int b = blockIdx.y, n0 = blockIdx.x * 64;
    int tid = threadIdx.x, wave = tid >> 6, lane = tid & 63;
    int l16 = lane & 15, quad = lane >> 4;
    const _Float16* xTb = xT + (size_t)b * N_ * C_;
    const _Float16* aRow = xTb + (size_t)(n0 + wave * 16 + l16) * C_ + quad * 8;

#pragma unroll
    for (int p = 0; p < 2; p++) {
        const _Float16* w = p ? wPh : wTh;
        const float* bias = p ? bPh : bTh;
        _Float16* outp = p ? phL : thL;
        float scale = p ? 1.0f : kLog2e;
        f32x4 acc[4] = {};
#pragma unroll
        for (int kc = 0; kc < 4; kc++) {
            f16x8 a = *(const f16x8*)(aRow + kc * 32);
#pragma unroll
            for (int t = 0; t < 4; t++) {
                f16x8 bb = *(const f16x8*)(w + (size_t)(t * 16 + l16) * C_ + kc * 32 + quad * 8);
                acc[t] = __builtin_amdgcn_mfma_f32_16x16x32_f16(a, bb, acc[t], 0, 0, 0);
            }
        }
        // value (row n_local = wave*16+quad*4+r, ci = t*16+l16) -> LDS swizzle
#pragma unroll
        for (int t = 0; t < 4; t++) {
            float bv = bias[t * 16 + l16];
            int base = wave * 1024 + (t >> 1) * 512
                     + ((t & 1) * 2 + (l16 >> 3)) * 128 + (l16 & 7);
#pragma unroll
            for (int r = 0; r < 4; r++)
                outp[base + (quad * 4 + r) * 8] =
                    (_Float16)((acc[t][r] + bv) * scale);
        }
    }
    {
        f32x4 acc[4] = {};
#pragma unroll
        for (int kc = 0; kc < 4; kc++) {
            f16x8 a = *(const f16x8*)(wG + (size_t)(wave * 16 + l16) * C_ + kc * 32 + quad * 8);
#pragma unroll
            for (int t = 0; t < 4; t++) {
                f16x8 bb = *(const f16x8*)(xTb + (size_t)(n0 + t * 16 + l16) * C_ + kc * 32 + quad * 8);
                acc[t] = __builtin_amdgcn_mfma_f32_16x16x32_f16(a, bb, acc[t], 0, 0, 0);
            }
        }
        // value (ci = wave*16+quad*4+r, m = n0 + t*16 + l16) -> LDS swizzle
#pragma unroll
        for (int t = 0; t < 4; t++) {
            int base = t * 1024 + ((l16 >> 2) * 16) * 16 + wave * 4 + (l16 & 3);
#pragma unroll
            for (int r = 0; r < 4; r++)
                gL[base + (quad * 4 + r) * 16] = (_Float16)(acc[t][r] + bG[wave * 16 + quad * 4 + r]);
        }
    }
    __syncthreads();
    // coalesced stores: block's 4 chunks are contiguous in each buffer
    {
        size_t gbase = (size_t)(b * 256 + (n0 >> 4)) * 1024;
        int off = tid * 8;
        *(f16x8*)(thS + gbase + off)        = *(const f16x8*)(thL + off);
        *(f16x8*)(thS + gbase + off + 2048) = *(const f16x8*)(thL + off + 2048);
        *(f16x8*)(phS + gbase + off)        = *(const f16x8*)(phL + off);
        *(f16x8*)(phS + gbase + off + 2048) = *(const f16x8*)(phL + off + 2048);
        *(f16x8*)(gS  + gbase + off)        = *(const f16x8*)(gL  + off);
        *(f16x8*)(gS  + gbase + off + 2048) = *(const f16x8*)(gL  + off + 2048);
    }
}

// ---------------------------------------------------------------------------
// K2a: nl2d[b][m] = -log2( sum_n exp2(S[n][m]) ), S = th(scaled)·ph^T.
// QK-lagged pipeline + 4 independent f32x4 accumulator lanes (no serial
// exp-add dependency chain).
// ---------------------------------------------------------------------------
__global__ __launch_bounds__(512) void k_stats(
    const _Float16* __restrict__ thS, const _Float16* __restrict__ phS,
    float* __restrict__ nl2d)
{
    __shared__ float Dp[8][64];
    int b = blockIdx.y, m0 = blockIdx.x * 64;
    int tid = threadIdx.x, wave = tid >> 6, lane = tid & 63;
    int l16 = lane & 15, quad = lane >> 4;

    f16x8 Bp[4][2];                      // phi fragments for cols m0..m0+63
#pragma unroll
    for (int t = 0; t < 4; t++) {
        const _Float16* cb = phS + (size_t)(b * 256 + (m0 >> 4) + t) * 1024 + lane * 8;
        Bp[t][0] = *(const f16x8*)(cb);
        Bp[t][1] = *(const f16x8*)(cb + 512);
    }
    f32x4 csum4[4] = {};                 // 16 independent accumulator chains
    const _Float16* pA = thS + (size_t)(b * 256 + wave * 32) * 1024 + lane * 8;
    f16x8 A0 = *(const f16x8*)pA, A1 = *(const f16x8*)(pA + 512);
    f32x4 Sp[4];
    {   // peel chunk 0: QK only
        const _Float16* pN = pA + 1024;
        f16x8 nA0 = *(const f16x8*)pN, nA1 = *(const f16x8*)(pN + 512);
        pA = pN;
#pragma unroll
        for (int t = 0; t < 4; t++) {
            f32x4 s = {0.f, 0.f, 0.f, 0.f};
            s = __builtin_amdgcn_mfma_f32_16x16x32_f16(A0, Bp[t][0], s, 0, 0, 0);
            Sp[t] = __builtin_amdgcn_mfma_f32_16x16x32_f16(A1, Bp[t][1], s, 0, 0, 0);
        }
        A0 = nA0; A1 = nA1;
    }
    for (int nc = 1; nc < 32; nc++) {
        const _Float16* pN = pA + ((nc < 31) ? 1024 : 0);
        f16x8 nA0 = *(const f16x8*)pN, nA1 = *(const f16x8*)(pN + 512);
        pA = pN;
        f32x4 Sc[4];
#pragma unroll
        for (int t = 0; t < 4; t++) {    // QK of chunk nc (issue first)
            f32x4 s = {0.f, 0.f, 0.f, 0.f};
            s = __builtin_amdgcn_mfma_f32_16x16x32_f16(A0, Bp[t][0], s, 0, 0, 0);
            Sc[t] = __builtin_amdgcn_mfma_f32_16x16x32_f16(A1, Bp[t][1], s, 0, 0, 0);
        }
#pragma unroll
        for (int t = 0; t < 4; t++) {    // exp+acc of chunk nc-1 (element-wise)
            f32x4 e;
            e[0] = __builtin_amdgcn_exp2f(Sp[t][0]);
            e[1] = __builtin_amdgcn_exp2f(Sp[t][1]);
            e[2] = __builtin_amdgcn_exp2f(Sp[t][2]);
            e[3] = __builtin_amdgcn_exp2f(Sp[t][3]);
            csum4[t] += e;
            Sp[t] = Sc[t];
        }
        A0 = nA0; A1 = nA1;
    }
#pragma unroll
    for (int t = 0; t < 4; t++) {        // drain chunk 31
        f32x4 e;
        e[0] = __builtin_amdgcn_exp2f(Sp[t][0]);
        e[1] = __builtin_amdgcn_exp2f(Sp[t][1]);
        e[2] = __builtin_amdgcn_exp2f(Sp[t][2]);
        e[3] = __builtin_amdgcn_exp2f(Sp[t][3]);
        csum4[t] += e;
    }
#pragma unroll
    for (int t = 0; t < 4; t++) {
        float s = (csum4[t][0] + csum4[t][1]) + (csum4[t][2] + csum4[t][3]);
        s += __shfl_xor(s, 16);
        s += __shfl_xor(s, 32);
        if (quad == 0) Dp[wave][t * 16 + l16] = s;
    }
    __syncthreads();
    if (tid < 64) {
        float d = Dp[0][tid] + Dp[1][tid] + Dp[2][tid] + Dp[3][tid]
                + Dp[4][tid] + Dp[5][tid] + Dp[6][tid] + Dp[7][tid];
        nl2d[(size_t)b * N_ + m0 + tid] = -__builtin_amdgcn_logf(d);   // v_log_f32 = log2
    }
}

// ---------------------------------------------------------------------------
// K2b: Y^T = g · softmax-weights.  S^T = ph·th^T, acc init = -log2(D[m]);
// P = exp2(S^T) stays in registers as the 16x16x16 B operand.
// Register budget tuned for 2 blocks/CU: Y = 64 AGPR, A/z 1-ahead prefetch,
// G just-in-time (issued at chunk top, consumed after exp), f16 LDS
// reduction (32 KiB).  __launch_bounds__(512,4) pins combined regs <= 128.
// ---------------------------------------------------------------------------
__global__ __launch_bounds__(512, 4) void k_attn(
    const _Float16* __restrict__ thS, const _Float16* __restrict__ phS,
    const _Float16* __restrict__ gS, const float* __restrict__ nl2d,
    _Float16* __restrict__ Yf)
{
    __shared__ _Float16 red[4][4096];    // 4 x 8 KiB f16 reduction slots
    int b = blockIdx.y, n0 = blockIdx.x * 64;
    int tid = threadIdx.x, wave = tid >> 6, lane = tid & 63;
    int l16 = lane & 15, quad = lane >> 4;
    const float* nlb = nl2d + (size_t)b * N_;

    f16x8 Bt[4][2];                      // theta fragments rows n0..n0+63
#pragma unroll
    for (int nt = 0; nt < 4; nt++) {
        const _Float16* cb = thS + (size_t)(b * 256 + (n0 >> 4) + nt) * 1024 + lane * 8;
        Bt[nt][0] = *(const f16x8*)(cb);
        Bt[nt][1] = *(const f16x8*)(cb + 512);
    }
    f32x4 Y[4][4] = {};                  // [ci_tile][n_tile] -> 64 AGPRs

    const int base = b * 256 + wave * 32;
    const _Float16* pA = phS + (size_t)base * 1024 + lane * 8;
    const _Float16* pG = gS  + (size_t)base * 1024 + lane * 16;
    const float*    pZ = nlb + wave * 512 + quad * 4;

    f16x8 A0 = *(const f16x8*)pA, A1 = *(const f16x8*)(pA + 512);
    f32x4 z = *(const f32x4*)pZ;

    for (int mc = 0; mc < 32; mc++) {
        int step = (mc < 31) ? 1024 : 0;
        // just-in-time G for THIS chunk (latency covered by QK + exp below)
        f16x8 G0 = *(const f16x8*)pG, G1 = *(const f16x8*)(pG + 8);
        // 1-ahead prefetch of A and z
        f16x8 nA0 = *(const f16x8*)(pA + step), nA1 = *(const f16x8*)(pA + step + 512);
        f32x4 nz = *(const f32x4*)(pZ + (step >> 6));
        pA += step; pG += step; pZ += (step >> 6);

        f32x4 S[4];
#pragma unroll
        for (int nt = 0; nt < 4; nt++) { // QK of chunk mc, bias folded into C
            f32x4 acc = z;
            acc = __builtin_amdgcn_mfma_f32_16x16x32_f16(A0, Bt[nt][0], acc, 0, 0, 0);
            S[nt] = __builtin_amdgcn_mfma_f32_16x16x32_f16(A1, Bt[nt][1], acc, 0, 0, 0);
        }
        f16x4 P[4];
#pragma unroll
        for (int nt = 0; nt < 4; nt++)
#pragma unroll
            for (int r = 0; r < 4; r++)
                P[nt][r] = (_Float16)__builtin_amdgcn_exp2f(S[nt][r]);

        f16x4 gf[4];
        gf[0] = __builtin_shufflevector(G0, G0, 0, 1, 2, 3);
        gf[1] = __builtin_shufflevector(G0, G0, 4, 5, 6, 7);
        gf[2] = __builtin_shufflevector(G1, G1, 0, 1, 2, 3);
        gf[3] = __builtin_shufflevector(G1, G1, 4, 5, 6, 7);
#pragma unroll
        for (int ct = 0; ct < 4; ct++)
#pragma unroll
            for (int nt = 0; nt < 4; nt++)
                Y[ct][nt] = __builtin_amdgcn_mfma_f32_16x16x16f16(gf[ct], P[nt], Y[ct][nt], 0, 0, 0);

        A0 = nA0; A1 = nA1; z = nz;
    }

    // ---- cross-wave reduction (f16 partials): waves 4-7 dump, 0-3 add ----
    if (wave >= 4) {
        _Float16* s = &red[wave - 4][lane * 4];
#pragma unroll
        for (int ct = 0; ct < 4; ct++)
#pragma unroll
            for (int nt = 0; nt < 4; nt++) {
                f16x4 h;
#pragma unroll
                for (int r = 0; r < 4; r++) h[r] = (_Float16)Y[ct][nt][r];
                *(f16x4*)(s + (ct * 4 + nt) * 256) = h;
            }
    }
    __syncthreads();
    if (wave < 4) {
        _Float16* s = &red[wave][lane * 4];
#pragma unroll
        for (int ct = 0; ct < 4; ct++)
#pragma unroll
            for (int nt = 0; nt < 4; nt++) {
                f16x4 h = *(const f16x4*)(s + (ct * 4 + nt) * 256);
                f16x4 o;
#pragma unroll
                for (int r = 0; r < 4; r++)
                    o[r] = (_Float16)(Y[ct][nt][r] + (float)h[r]);
                *(f16x4*)(s + (ct * 4 + nt) * 256) = o;
            }
    }
    __syncthreads();
    // cooperative store: thread t -> row n = t>>3, ci group = (t&7)*8
    {
        int n = tid >> 3, k8 = tid & 7;
        _Float16 vals[8];
#pragma unroll
        for (int j = 0; j < 8; j++) {
            int ci = k8 * 8 + j;
            int ct = ci >> 4, jj = ci & 15, q = jj >> 2, r = jj & 3;
            int idx = (ct * 4 + (n >> 4)) * 256 + (q * 16 + (n & 15)) * 4 + r;
            vals[j] = (_Float16)(((float)red[0][idx] + (float)red[1][idx])
                               + ((float)red[2][idx] + (float)red[3][idx]));
        }
        *(f16x8*)(Yf + ((size_t)b * N_ + n0 + n) * CI_ + k8 * 8) = *(f16x8*)vals;
    }
}

// ---------------------------------------------------------------------------
// K3: out[b][c][n] = W_w @ Y^T + W_b + x (residual).
// ---------------------------------------------------------------------------
__global__ __launch_bounds__(256) void k_out(
    const _Float16* __restrict__ wW, const float* __restrict__ Wb,
    const _Float16* __restrict__ Yf, const float* __restrict__ x,
    float* __restrict__ out)
{
    int b = blockIdx.y, n0 = blockIdx.x * 64;
    int tid = threadIdx.x, wave = tid >> 6, lane = tid & 63;
    int l16 = lane & 15, quad = lane >> 4;
    f16x8 Af[2][2];
#pragma unroll
    for (int rt = 0; rt < 2; rt++)
#pragma unroll
        for (int kc = 0; kc < 2; kc++)
            Af[rt][kc] = *(const f16x8*)(wW + (size_t)(wave * 32 + rt * 16 + l16) * CI_ + kc * 32 + quad * 8);
    f32x4 acc[2][4] = {};
#pragma unroll
    for (int t = 0; t < 4; t++) {
        const _Float16* yp = Yf + ((size_t)b * N_ + n0 + t * 16 + l16) * CI_;
        f16x8 b0 = *(const f16x8*)(yp + quad * 8);
        f16x8 b1 = *(const f16x8*)(yp + 32 + quad * 8);
#pragma unroll
        for (int rt = 0; rt < 2; rt++) {
            acc[rt][t] = __builtin_amdgcn_mfma_f32_16x16x32_f16(Af[rt][0], b0, acc[rt][t], 0, 0, 0);
            acc[rt][t] = __builtin_amdgcn_mfma_f32_16x16x32_f16(Af[rt][1], b1, acc[rt][t], 0, 0, 0);
        }
    }
#pragma unroll
    for (int rt = 0; rt < 2; rt++)
#pragma unroll
        for (int t = 0; t < 4; t++)
#pragma unroll
            for (int r = 0; r < 4; r++) {
                int c = wave * 32 + rt * 16 + quad * 4 + r;
                size_t o = ((size_t)b * C_ + c) * N_ + n0 + t * 16 + l16;
                out[o] = acc[rt][t][r] + Wb[c] + x[o];
            }
}

// ---------------------------------------------------------------------------
extern "C" void kernel_launch(void* const* d_in, const int* in_sizes, int n_in,
                              void* d_out, int out_size, void* d_ws, size_t ws_size,
                              hipStream_t stream)
{
    const float* x    = (const float*)d_in[0];
    const float* g_w  = (const float*)d_in[1];
    const float* g_b  = (const float*)d_in[2];
    const float* th_w = (const float*)d_in[3];
    const float* th_b = (const float*)d_in[4];
    const float* ph_w = (const float*)d_in[5];
    const float* ph_b = (const float*)d_in[6];
    const float* W_w  = (const float*)d_in[7];
    const float* W_b  = (const float*)d_in[8];
    float* out = (float*)d_out;

    char* ws = (char*)d_ws;
    _Float16* xT  = (_Float16*)(ws);                  // [B][N][C]  8 MiB
    _Float16* thS = (_Float16*)(ws + 8388608);        // swizzled   4 MiB
    _Float16* phS = (_Float16*)(ws + 12582912);       // swizzled   4 MiB
    _Float16* gS  = (_Float16*)(ws + 16777216);       // swizzled   4 MiB
    _Float16* Yf  = (_Float16*)(ws + 20971520);       // [B][N][CI] 4 MiB
    float*    nl2d= (float*)   (ws + 25165824);       // [B][N]     128 KiB
    _Float16* wTh = (_Float16*)(ws + 25296896);
    _Float16* wPh = (_Float16*)(ws + 25313280);
    _Float16* wG  = (_Float16*)(ws + 25329664);
    _Float16* wW  = (_Float16*)(ws + 25346048);       // end ~25.4 MiB

    hipLaunchKernelGGL(k_transpose, dim3(64, 2, 8), dim3(256), 0, stream, x, xT);
    hipLaunchKernelGGL(k_wconv, dim3(128), dim3(256), 0, stream,
                       th_w, ph_w, g_w, W_w, wTh, wPh, wG, wW);
    hipLaunchKernelGGL(k_proj, dim3(64, 8), dim3(256), 0, stream,
                       xT, wTh, wPh, wG, th_b, ph_b, g_b, thS, phS, gS);
    hipLaunchKernelGGL(k_stats, dim3(64, 8), dim3(512), 0, stream, thS, phS, nl2d);
    hipLaunchKernelGGL(k_attn, dim3(64, 8), dim3(512), 0, stream, thS, phS, gS, nl2d, Yf);
    hipLaunchKernelGGL(k_out, dim3(64, 8), dim3(256), 0, stream, wW, W_b, Yf, x, out);
}

// Round 10
// 161.148 us; speedup vs baseline: 1.1225x; 1.1225x over previous
//
#include <hip/hip_runtime.h>

#define B_ 8
#define C_ 128
#define CI_ 64
#define N_ 4096

typedef _Float16 f16x8 __attribute__((ext_vector_type(8)));
typedef _Float16 f16x4 __attribute__((ext_vector_type(4)));
typedef float   f32x4  __attribute__((ext_vector_type(4)));

// Swizzled operand layouts (per batch, 256 chunks of 16 rows):
//  thS/phS: elem[((b*256+mc)*2 + half)*512 + lane*8 + e]
//           = X[row = mc*16 + (lane&15)][ci = half*32 + (lane>>4)*8 + e]
//  gS:      elem[(b*256+mc)*1024 + lane*16 + (ct*4 + j)]
//           = g[ci = ct*16 + (lane&15)][m = mc*16 + (lane>>4)*4 + j]
// Chunk stride 1024 elems; every streamed wave load is a coalesced 1 KiB
// dwordx4.

// ---------------------------------------------------------------------------
// K0: convert the four weight matrices fp32 -> f16 (each 8192 elems)
// ---------------------------------------------------------------------------
__global__ __launch_bounds__(256) void k_wconv(
    const float* __restrict__ thw, const float* __restrict__ phw,
    const float* __restrict__ gw,  const float* __restrict__ ww,
    _Float16* __restrict__ wTh, _Float16* __restrict__ wPh,
    _Float16* __restrict__ wG,  _Float16* __restrict__ wW)
{
    int i = blockIdx.x * 256 + threadIdx.x;   // 0..32767
    int which = i >> 13, j = i & 8191;
    if (which == 0)      wTh[j] = (_Float16)thw[j];
    else if (which == 1) wPh[j] = (_Float16)phw[j];
    else if (which == 2) wG[j]  = (_Float16)gw[j];
    else                 wW[j]  = (_Float16)ww[j];
}

// ---------------------------------------------------------------------------
// K1: fused transpose + projections.  Loads the 128x64 x-tile fp32, writes it
// transposed into a fragment-swizzled LDS tile (A-operand reads become
// conflict-free ds_read_b128), runs the three GEMMs, stages outputs in LDS,
// stores coalesced f16x8 to thS (pre-scaled log2e) / phS / gS.
// ---------------------------------------------------------------------------
__global__ __launch_bounds__(256) void k_prep(
    const float* __restrict__ x,
    const _Float16* __restrict__ wTh, const _Float16* __restrict__ wPh,
    const _Float16* __restrict__ wG,
    const float* __restrict__ bTh, const float* __restrict__ bPh,
    const float* __restrict__ bG,
    _Float16* __restrict__ thS, _Float16* __restrict__ phS,
    _Float16* __restrict__ gS)
{
    __shared__ _Float16 xL[8192];                          // 16 KiB x-tile
    __shared__ _Float16 thL[4096], phL[4096], gL[4096];    // 24 KiB staging
    const float kLog2e = 1.44269504088896f;
    int b = blockIdx.y, n0 = blockIdx.x * 64;
    int tid = threadIdx.x, wave = tid >> 6, lane = tid & 63;
    int l16 = lane & 15, quad = lane >> 4;

    // ---- load + transpose x[b][0:128][n0:n0+64] into swizzled LDS ----
    // xL idx(nL,c) = (nL>>4)*2048 + (c>>5)*512 + ((c>>3)&3)*128 + (nL&15)*8 + (c&7)
#pragma unroll
    for (int i = 0; i < 8; i++) {
        int c = (tid >> 4) + i * 16;
        int n4 = (tid & 15) * 4;
        f32x4 v = *(const f32x4*)(x + ((size_t)b * C_ + c) * N_ + n0 + n4);
        int cpart = (c >> 5) * 512 + ((c >> 3) & 3) * 128 + (c & 7);
#pragma unroll
        for (int j = 0; j < 4; j++) {
            int nL = n4 + j;
            xL[(nL >> 4) * 2048 + cpart + (nL & 15) * 8] = (_Float16)v[j];
        }
    }
    __syncthreads();

    // ---- theta / phi GEMMs (A from LDS, rows n0+wave*16..) ----
#pragma unroll
    for (int p = 0; p < 2; p++) {
        const _Float16* w = p ? wPh : wTh;
        const float* bias = p ? bPh : bTh;
        _Float16* outp = p ? phL : thL;
        float scale = p ? 1.0f : kLog2e;
        f32x4 acc[4] = {};
#pragma unroll
        for (int kc = 0; kc < 4; kc++) {
            f16x8 a = *(const f16x8*)(xL + wave * 2048 + kc * 512 + lane * 8);
#pragma unroll
            for (int t = 0; t < 4; t++) {
                f16x8 bb = *(const f16x8*)(w + (size_t)(t * 16 + l16) * C_ + kc * 32 + quad * 8);
                acc[t] = __builtin_amdgcn_mfma_f32_16x16x32_f16(a, bb, acc[t], 0, 0, 0);
            }
        }
        // value (row nL = wave*16+quad*4+r, ci = t*16+l16) -> LDS swizzle
#pragma unroll
        for (int t = 0; t < 4; t++) {
            float bv = bias[t * 16 + l16];
            int base = wave * 1024 + (t >> 1) * 512
                     + ((t & 1) * 2 + (l16 >> 3)) * 128 + (l16 & 7);
#pragma unroll
            for (int r = 0; r < 4; r++)
                outp[base + (quad * 4 + r) * 8] =
                    (_Float16)((acc[t][r] + bv) * scale);
        }
    }
    // ---- g GEMM (A = wG rows ci, B = x-tile rows from LDS) ----
    {
        f32x4 acc[4] = {};
#pragma unroll
        for (int kc = 0; kc < 4; kc++) {
            f16x8 a = *(const f16x8*)(wG + (size_t)(wave * 16 + l16) * C_ + kc * 32 + quad * 8);
#pragma unroll
            for (int t = 0; t < 4; t++) {
                f16x8 bb = *(const f16x8*)(xL + t * 2048 + kc * 512 + lane * 8);
                acc[t] = __builtin_amdgcn_mfma_f32_16x16x32_f16(a, bb, acc[t], 0, 0, 0);
            }
        }
        // value (ci = wave*16+quad*4+r, m = n0+t*16+l16) -> LDS swizzle
#pragma unroll
        for (int t = 0; t < 4; t++) {
            int base = t * 1024 + ((l16 >> 2) * 16) * 16 + wave * 4 + (l16 & 3);
#pragma unroll
            for (int r = 0; r < 4; r++)
                gL[base + (quad * 4 + r) * 16] = (_Float16)(acc[t][r] + bG[wave * 16 + quad * 4 + r]);
        }
    }
    __syncthreads();
    // coalesced stores: block's 4 chunks are contiguous in each buffer
    {
        size_t gbase = (size_t)(b * 256 + (n0 >> 4)) * 1024;
        int off = tid * 8;
        *(f16x8*)(thS + gbase + off)        = *(const f16x8*)(thL + off);
        *(f16x8*)(thS + gbase + off + 2048) = *(const f16x8*)(thL + off + 2048);
        *(f16x8*)(phS + gbase + off)        = *(const f16x8*)(phL + off);
        *(f16x8*)(phS + gbase + off + 2048) = *(const f16x8*)(phL + off + 2048);
        *(f16x8*)(gS  + gbase + off)        = *(const f16x8*)(gL  + off);
        *(f16x8*)(gS  + gbase + off + 2048) = *(const f16x8*)(gL  + off + 2048);
    }
}

// ---------------------------------------------------------------------------
// K2: nl2d[b][m] = -log2( sum_n exp2(S[n][m]) ), S = th(scaled)·ph^T.
// QK-lagged pipeline + independent f32x4 accumulator lanes.
// ---------------------------------------------------------------------------
__global__ __launch_bounds__(512) void k_stats(
    const _Float16* __restrict__ thS, const _Float16* __restrict__ phS,
    float* __restrict__ nl2d)
{
    __shared__ float Dp[8][64];
    int b = blockIdx.y, m0 = blockIdx.x * 64;
    int tid = threadIdx.x, wave = tid >> 6, lane = tid & 63;
    int l16 = lane & 15, quad = lane >> 4;

    f16x8 Bp[4][2];                      // phi fragments for cols m0..m0+63
#pragma unroll
    for (int t = 0; t < 4; t++) {
        const _Float16* cb = phS + (size_t)(b * 256 + (m0 >> 4) + t) * 1024 + lane * 8;
        Bp[t][0] = *(const f16x8*)(cb);
        Bp[t][1] = *(const f16x8*)(cb + 512);
    }
    f32x4 csum4[4] = {};                 // 16 independent accumulator chains
    const _Float16* pA = thS + (size_t)(b * 256 + wave * 32) * 1024 + lane * 8;
    f16x8 A0 = *(const f16x8*)pA, A1 = *(const f16x8*)(pA + 512);
    f32x4 Sp[4];
    {   // peel chunk 0: QK only
        const _Float16* pN = pA + 1024;
        f16x8 nA0 = *(const f16x8*)pN, nA1 = *(const f16x8*)(pN + 512);
        pA = pN;
#pragma unroll
        for (int t = 0; t < 4; t++) {
            f32x4 s = {0.f, 0.f, 0.f, 0.f};
            s = __builtin_amdgcn_mfma_f32_16x16x32_f16(A0, Bp[t][0], s, 0, 0, 0);
            Sp[t] = __builtin_amdgcn_mfma_f32_16x16x32_f16(A1, Bp[t][1], s, 0, 0, 0);
        }
        A0 = nA0; A1 = nA1;
    }
    for (int nc = 1; nc < 32; nc++) {
        const _Float16* pN = pA + ((nc < 31) ? 1024 : 0);
        f16x8 nA0 = *(const f16x8*)pN, nA1 = *(const f16x8*)(pN + 512);
        pA = pN;
        f32x4 Sc[4];
#pragma unroll
        for (int t = 0; t < 4; t++) {    // QK of chunk nc (issue first)
            f32x4 s = {0.f, 0.f, 0.f, 0.f};
            s = __builtin_amdgcn_mfma_f32_16x16x32_f16(A0, Bp[t][0], s, 0, 0, 0);
            Sc[t] = __builtin_amdgcn_mfma_f32_16x16x32_f16(A1, Bp[t][1], s, 0, 0, 0);
        }
#pragma unroll
        for (int t = 0; t < 4; t++) {    // exp+acc of chunk nc-1
            f32x4 e;
            e[0] = __builtin_amdgcn_exp2f(Sp[t][0]);
            e[1] = __builtin_amdgcn_exp2f(Sp[t][1]);
            e[2] = __builtin_amdgcn_exp2f(Sp[t][2]);
            e[3] = __builtin_amdgcn_exp2f(Sp[t][3]);
            csum4[t] += e;
            Sp[t] = Sc[t];
        }
        A0 = nA0; A1 = nA1;
    }
#pragma unroll
    for (int t = 0; t < 4; t++) {        // drain chunk 31
        f32x4 e;
        e[0] = __builtin_amdgcn_exp2f(Sp[t][0]);
        e[1] = __builtin_amdgcn_exp2f(Sp[t][1]);
        e[2] = __builtin_amdgcn_exp2f(Sp[t][2]);
        e[3] = __builtin_amdgcn_exp2f(Sp[t][3]);
        csum4[t] += e;
    }
#pragma unroll
    for (int t = 0; t < 4; t++) {
        float s = (csum4[t][0] + csum4[t][1]) + (csum4[t][2] + csum4[t][3]);
        s += __shfl_xor(s, 16);
        s += __shfl_xor(s, 32);
        if (quad == 0) Dp[wave][t * 16 + l16] = s;
    }
    __syncthreads();
    if (tid < 64) {
        float d = Dp[0][tid] + Dp[1][tid] + Dp[2][tid] + Dp[3][tid]
                + Dp[4][tid] + Dp[5][tid] + Dp[6][tid] + Dp[7][tid];
        nl2d[(size_t)b * N_ + m0 + tid] = -__builtin_amdgcn_logf(d);   // v_log_f32 = log2
    }
}

// ---------------------------------------------------------------------------
// K3: fused attention + output projection + residual.
// Main loop: S^T = ph·th^T (acc init -log2 D), P = exp2 in registers as the
// 16x16x16 B operand, Y accumulated in AGPRs.  Epilogue: LDS tree-reduce the
// 8 wave partials, combine, then per-wave W GEMM (A = W_w fragments, B = Y
// fragments from LDS) and out = W·Y + W_b + x.
// ---------------------------------------------------------------------------
__global__ __launch_bounds__(512, 4) void k_attn_out(
    const _Float16* __restrict__ thS, const _Float16* __restrict__ phS,
    const _Float16* __restrict__ gS, const float* __restrict__ nl2d,
    const _Float16* __restrict__ wW, const float* __restrict__ Wb,
    const float* __restrict__ x, float* __restrict__ out)
{
    __shared__ _Float16 red[4][4096];    // 4 x 8 KiB f16 reduction slots
    int b = blockIdx.y, n0 = blockIdx.x * 64;
    int tid = threadIdx.x, wave = tid >> 6, lane = tid & 63;
    int l16 = lane & 15, quad = lane >> 4;
    const float* nlb = nl2d + (size_t)b * N_;

    f16x8 Bt[4][2];                      // theta fragments rows n0..n0+63
#pragma unroll
    for (int nt = 0; nt < 4; nt++) {
        const _Float16* cb = thS + (size_t)(b * 256 + (n0 >> 4) + nt) * 1024 + lane * 8;
        Bt[nt][0] = *(const f16x8*)(cb);
        Bt[nt][1] = *(const f16x8*)(cb + 512);
    }
    f32x4 Y[4][4] = {};                  // [ci_tile][n_tile] -> 64 AGPRs

    const int base = b * 256 + wave * 32;
    const _Float16* pA = phS + (size_t)base * 1024 + lane * 8;
    const _Float16* pG = gS  + (size_t)base * 1024 + lane * 16;
    const float*    pZ = nlb + wave * 512 + quad * 4;

    f16x8 A0 = *(const f16x8*)pA, A1 = *(const f16x8*)(pA + 512);
    f32x4 z = *(const f32x4*)pZ;

    for (int mc = 0; mc < 32; mc++) {
        int step = (mc < 31) ? 1024 : 0;
        f16x8 G0 = *(const f16x8*)pG, G1 = *(const f16x8*)(pG + 8);
        f16x8 nA0 = *(const f16x8*)(pA + step), nA1 = *(const f16x8*)(pA + step + 512);
        f32x4 nz = *(const f32x4*)(pZ + (step >> 6));
        pA += step; pG += step; pZ += (step >> 6);

        f32x4 S[4];
#pragma unroll
        for (int nt = 0; nt < 4; nt++) { // QK of chunk mc, bias folded into C
            f32x4 acc = z;
            acc = __builtin_amdgcn_mfma_f32_16x16x32_f16(A0, Bt[nt][0], acc, 0, 0, 0);
            S[nt] = __builtin_amdgcn_mfma_f32_16x16x32_f16(A1, Bt[nt][1], acc, 0, 0, 0);
        }
        f16x4 P[4];
#pragma unroll
        for (int nt = 0; nt < 4; nt++)
#pragma unroll
            for (int r = 0; r < 4; r++)
                P[nt][r] = (_Float16)__builtin_amdgcn_exp2f(S[nt][r]);

        f16x4 gf[4];
        gf[0] = __builtin_shufflevector(G0, G0, 0, 1, 2, 3);
        gf[1] = __builtin_shufflevector(G0, G0, 4, 5, 6, 7);
        gf[2] = __builtin_shufflevector(G1, G1, 0, 1, 2, 3);
        gf[3] = __builtin_shufflevector(G1, G1, 4, 5, 6, 7);
#pragma unroll
        for (int ct = 0; ct < 4; ct++)
#pragma unroll
            for (int nt = 0; nt < 4; nt++)
                Y[ct][nt] = __builtin_amdgcn_mfma_f32_16x16x16f16(gf[ct], P[nt], Y[ct][nt], 0, 0, 0);

        A0 = nA0; A1 = nA1; z = nz;
    }

    // ---- cross-wave reduction (f16 partials): waves 4-7 dump, 0-3 add ----
    if (wave >= 4) {
        _Float16* s = &red[wave - 4][lane * 4];
#pragma unroll
        for (int ct = 0; ct < 4; ct++)
#pragma unroll
            for (int nt = 0; nt < 4; nt++) {
                f16x4 h;
#pragma unroll
                for (int r = 0; r < 4; r++) h[r] = (_Float16)Y[ct][nt][r];
                *(f16x4*)(s + (ct * 4 + nt) * 256) = h;
            }
    }
    __syncthreads();
    if (wave < 4) {
        _Float16* s = &red[wave][lane * 4];
#pragma unroll
        for (int ct = 0; ct < 4; ct++)
#pragma unroll
            for (int nt = 0; nt < 4; nt++) {
                f16x4 h = *(const f16x4*)(s + (ct * 4 + nt) * 256);
                f16x4 o;
#pragma unroll
                for (int r = 0; r < 4; r++)
                    o[r] = (_Float16)(Y[ct][nt][r] + (float)h[r]);
                *(f16x4*)(s + (ct * 4 + nt) * 256) = o;
            }
    }
    __syncthreads();
    // ---- combine 4 slots into red[0] (packed f16 adds) ----
    {
        int off = tid * 8;
        f16x8 s0 = *(const f16x8*)&red[0][off];
        f16x8 s1 = *(const f16x8*)&red[1][off];
        f16x8 s2 = *(const f16x8*)&red[2][off];
        f16x8 s3 = *(const f16x8*)&red[3][off];
        *(f16x8*)&red[0][off] = (s0 + s1) + (s2 + s3);
    }
    __syncthreads();
    // ---- fused output projection: wave w owns c-rows w*16..w*16+15 ----
    {
        f16x8 Wf[2];
        const _Float16* wp = wW + (size_t)(wave * 16 + l16) * CI_ + quad * 8;
        Wf[0] = *(const f16x8*)(wp);
        Wf[1] = *(const f16x8*)(wp + 32);
        const _Float16* r0 = &red[0][0];
        f32x4 oacc[4] = {};
#pragma unroll
        for (int nt = 0; nt < 4; nt++) {
#pragma unroll
            for (int kc = 0; kc < 2; kc++) {
                int ct = kc * 2 + (quad >> 1);
                int bidx = (ct * 4 + nt) * 256 + (quad & 1) * 128 + l16 * 4;
                f16x4 lo = *(const f16x4*)(r0 + bidx);
                f16x4 hi = *(const f16x4*)(r0 + bidx + 64);
                f16x8 yb;
                yb[0] = lo[0]; yb[1] = lo[1]; yb[2] = lo[2]; yb[3] = lo[3];
                yb[4] = hi[0]; yb[5] = hi[1]; yb[6] = hi[2]; yb[7] = hi[3];
                oacc[nt] = __builtin_amdgcn_mfma_f32_16x16x32_f16(Wf[kc], yb, oacc[nt], 0, 0, 0);
            }
        }
        const float* xb = x   + ((size_t)b * C_ + wave * 16) * N_ + n0;
        float*       ob = out + ((size_t)b * C_ + wave * 16) * N_ + n0;
#pragma unroll
        for (int nt = 0; nt < 4; nt++)
#pragma unroll
            for (int r = 0; r < 4; r++) {
                size_t o = (size_t)(quad * 4 + r) * N_ + nt * 16 + l16;
                ob[o] = oacc[nt][r] + Wb[wave * 16 + quad * 4 + r] + xb[o];
            }
    }
}

// ---------------------------------------------------------------------------
extern "C" void kernel_launch(void* const* d_in, const int* in_sizes, int n_in,
                              void* d_out, int out_size, void* d_ws, size_t ws_size,
                              hipStream_t stream)
{
    const float* x    = (const float*)d_in[0];
    const float* g_w  = (const float*)d_in[1];
    const float* g_b  = (const float*)d_in[2];
    const float* th_w = (const float*)d_in[3];
    const float* th_b = (const float*)d_in[4];
    const float* ph_w = (const float*)d_in[5];
    const float* ph_b = (const float*)d_in[6];
    const float* W_w  = (const float*)d_in[7];
    const float* W_b  = (const float*)d_in[8];
    float* out = (float*)d_out;

    char* ws = (char*)d_ws;
    _Float16* thS = (_Float16*)(ws);                  // swizzled   4 MiB
    _Float16* phS = (_Float16*)(ws + 4194304);        // swizzled   4 MiB
    _Float16* gS  = (_Float16*)(ws + 8388608);        // swizzled   4 MiB
    float*    nl2d= (float*)   (ws + 12582912);       // [B][N]     128 KiB
    _Float16* wTh = (_Float16*)(ws + 12713984);
    _Float16* wPh = (_Float16*)(ws + 12730368);
    _Float16* wG  = (_Float16*)(ws + 12746752);
    _Float16* wW  = (_Float16*)(ws + 12763136);       // end ~12.2 MiB

    hipLaunchKernelGGL(k_wconv, dim3(128), dim3(256), 0, stream,
                       th_w, ph_w, g_w, W_w, wTh, wPh, wG, wW);
    hipLaunchKernelGGL(k_prep, dim3(64, 8), dim3(256), 0, stream,
                       x, wTh, wPh, wG, th_b, ph_b, g_b, thS, phS, gS);
    hipLaunchKernelGGL(k_stats, dim3(64, 8), dim3(512), 0, stream, thS, phS, nl2d);
    hipLaunchKernelGGL(k_attn_out, dim3(64, 8), dim3(512), 0, stream,
                       thS, phS, gS, nl2d, wW, W_b, x, out);
}